// Round 3
// baseline (110.685 us; speedup 1.0000x reference)
//
#include <hip/hip_runtime.h>

// PathSampling: per node, score 32 paths (sum of centrality over masked
// prefix), stable top-8, emit selected masked paths + their edge rows.
//
// Round 3: fix nontemporal builtin types (clang ext_vector, not HIP int4).
// Cooperative (coalesced) edge copy via LDS-published winner rows;
// non-temporal hints on streaming traffic to keep centrality L2-resident.

#define N_NODE   100000
#define N_PATH   32
#define L_PATH   8
#define K_PATH   8

typedef int v4i __attribute__((ext_vector_type(4)));

__global__ __launch_bounds__(256) void path_sampling_kernel(
    const int*   __restrict__ paths,
    const int*   __restrict__ edge_ids,
    const int*   __restrict__ rand_lens,
    const float* __restrict__ centrality,
    int*         __restrict__ out_paths,   // [N_NODE, K_PATH, L_PATH]
    int*         __restrict__ out_edges)   // [N_NODE, K_PATH, L_PATH-1]
{
    // winner source path index per (node-in-block, rank)
    __shared__ int wsrc[8][8];

    const int t    = threadIdx.x;
    const int lane = t & 31;                    // path within node
    const int n8   = t >> 5;                    // node within block
    const int node = blockIdx.x * 8 + n8;       // grid*8 == N_NODE exactly

    const size_t row = (size_t)node * N_PATH + lane;

    // Coalesced 32B load of this path's 8 node ids (streamed once -> nt).
    const v4i* p4 = (const v4i*)(paths + row * L_PATH);
    v4i pa = __builtin_nontemporal_load(p4);
    v4i pb = __builtin_nontemporal_load(p4 + 1);
    int len = rand_lens[row];                   // keep positions j <= len

    int mp[8] = {pa.x, pa.y, pa.z, pa.w, pb.x, pb.y, pb.z, pb.w};

    // Mask + predicated gather. Masked slots contribute exactly 0.0f and
    // issue no load (saves TA line-touches).
    float c[8];
    #pragma unroll
    for (int j = 0; j < 8; ++j) {
        if (j > len) mp[j] = -1;
        c[j] = (mp[j] < 0) ? 0.0f : centrality[mp[j]];
    }

    // numpy pairwise-tree summation order for bit-exact score match.
    const float score = ((c[0] + c[1]) + (c[2] + c[3]))
                      + ((c[4] + c[5]) + (c[6] + c[7]));

    // Stable descending rank (ties -> lower index wins), matches lax.top_k.
    int rank = 0;
    #pragma unroll
    for (int j = 0; j < 32; ++j) {
        float sj = __shfl(score, j, 32);
        rank += (sj > score) || (sj == score && j < lane);
    }

    if (rank < K_PATH) {
        wsrc[n8][rank] = lane;                  // publish winner src row

        // paths_sel store: winner already holds mp[] in registers.
        const size_t obase = (size_t)node * K_PATH + rank;
        v4i* op = (v4i*)(out_paths + obase * L_PATH);
        v4i lo = {mp[0], mp[1], mp[2], mp[3]};
        v4i hi = {mp[4], mp[5], mp[6], mp[7]};
        __builtin_nontemporal_store(lo, op);
        __builtin_nontemporal_store(hi, op + 1);
    }

    __syncthreads();   // all threads reach here (no early return)

    // Cooperative edge copy: 8 selected rows x 7 ints = 56 ints per node.
    // All 32 lanes of the node participate: lane handles flats {lane, lane+32}.
    // Loads are 7-dword runs per rank-row (segment-coalesced); stores are
    // fully coalesced into the contiguous output region.
    const int* ebase = edge_ids + (size_t)node * (N_PATH * (L_PATH - 1));
    int*       edst  = out_edges + (size_t)node * (K_PATH * (L_PATH - 1));

    {
        const int f   = lane;                   // 0..31
        const int r   = f / 7;                  // compiler magic-mul
        const int col = f - r * 7;
        const int srow = wsrc[n8][r];
        int v = __builtin_nontemporal_load(ebase + srow * 7 + col);
        __builtin_nontemporal_store(v, edst + f);
    }
    if (lane < 24) {
        const int f   = lane + 32;              // 32..55
        const int r   = f / 7;
        const int col = f - r * 7;
        const int srow = wsrc[n8][r];
        int v = __builtin_nontemporal_load(ebase + srow * 7 + col);
        __builtin_nontemporal_store(v, edst + f);
    }
}

extern "C" void kernel_launch(void* const* d_in, const int* in_sizes, int n_in,
                              void* d_out, int out_size, void* d_ws, size_t ws_size,
                              hipStream_t stream) {
    const int*   paths      = (const int*)  d_in[0];
    const int*   edge_ids   = (const int*)  d_in[1];
    const int*   rand_lens  = (const int*)  d_in[2];
    const float* centrality = (const float*)d_in[3];
    // d_in[4] is k_path (scalar, known == 8)

    int* out_paths = (int*)d_out;
    int* out_edges = out_paths + (size_t)N_NODE * K_PATH * L_PATH;

    const int nodes_per_block = 8;   // 256 threads / 32 paths
    const int grid = N_NODE / nodes_per_block;  // 12500, exact

    path_sampling_kernel<<<grid, 256, 0, stream>>>(
        paths, edge_ids, rand_lens, centrality, out_paths, out_edges);
}

// Round 4
// 78.674 us; speedup vs baseline: 1.4069x; 1.4069x over previous
//
#include <hip/hip_runtime.h>

// PathSampling: per node, score 32 paths (sum of centrality over masked
// prefix), stable top-8, emit selected masked paths + their edge rows.
//
// Round 4: revert ALL nontemporal hints (they evicted the working set from
// Infinity Cache between timed replays -> 75->110us regression). Keep the
// cooperative (coalesced) edge copy via LDS-published winner rows.

#define N_NODE   100000
#define N_PATH   32
#define L_PATH   8
#define K_PATH   8

typedef int v4i __attribute__((ext_vector_type(4)));

__global__ __launch_bounds__(256) void path_sampling_kernel(
    const int*   __restrict__ paths,
    const int*   __restrict__ edge_ids,
    const int*   __restrict__ rand_lens,
    const float* __restrict__ centrality,
    int*         __restrict__ out_paths,   // [N_NODE, K_PATH, L_PATH]
    int*         __restrict__ out_edges)   // [N_NODE, K_PATH, L_PATH-1]
{
    // winner source path index per (node-in-block, rank)
    __shared__ int wsrc[8][8];

    const int t    = threadIdx.x;
    const int lane = t & 31;                    // path within node
    const int n8   = t >> 5;                    // node within block
    const int node = blockIdx.x * 8 + n8;       // grid*8 == N_NODE exactly

    const size_t row = (size_t)node * N_PATH + lane;

    // Coalesced 32B load of this path's 8 node ids.
    const v4i* p4 = (const v4i*)(paths + row * L_PATH);
    v4i pa = p4[0];
    v4i pb = p4[1];
    int len = rand_lens[row];                   // keep positions j <= len

    int mp[8] = {pa.x, pa.y, pa.z, pa.w, pb.x, pb.y, pb.z, pb.w};

    // Mask + predicated gather. Masked slots contribute exactly 0.0f and
    // issue no load (saves TA line-touches).
    float c[8];
    #pragma unroll
    for (int j = 0; j < 8; ++j) {
        if (j > len) mp[j] = -1;
        c[j] = (mp[j] < 0) ? 0.0f : centrality[mp[j]];
    }

    // numpy pairwise-tree summation order for bit-exact score match.
    const float score = ((c[0] + c[1]) + (c[2] + c[3]))
                      + ((c[4] + c[5]) + (c[6] + c[7]));

    // Stable descending rank (ties -> lower index wins), matches lax.top_k.
    int rank = 0;
    #pragma unroll
    for (int j = 0; j < 32; ++j) {
        float sj = __shfl(score, j, 32);
        rank += (sj > score) || (sj == score && j < lane);
    }

    if (rank < K_PATH) {
        wsrc[n8][rank] = lane;                  // publish winner src row

        // paths_sel store: winner already holds mp[] in registers.
        const size_t obase = (size_t)node * K_PATH + rank;
        v4i* op = (v4i*)(out_paths + obase * L_PATH);
        v4i lo = {mp[0], mp[1], mp[2], mp[3]};
        v4i hi = {mp[4], mp[5], mp[6], mp[7]};
        op[0] = lo;
        op[1] = hi;
    }

    __syncthreads();   // all threads reach here (no early return)

    // Cooperative edge copy: 8 selected rows x 7 ints = 56 ints per node.
    // All 32 lanes of the node participate: lane handles flats {lane, lane+32}.
    // Loads are 7-dword runs per rank-row (segment-coalesced); stores are
    // fully coalesced into the contiguous output region.
    const int* ebase = edge_ids + (size_t)node * (N_PATH * (L_PATH - 1));
    int*       edst  = out_edges + (size_t)node * (K_PATH * (L_PATH - 1));

    {
        const int f   = lane;                   // 0..31
        const int r   = f / 7;                  // compiler magic-mul
        const int col = f - r * 7;
        const int srow = wsrc[n8][r];
        edst[f] = ebase[srow * 7 + col];
    }
    if (lane < 24) {
        const int f   = lane + 32;              // 32..55
        const int r   = f / 7;
        const int col = f - r * 7;
        const int srow = wsrc[n8][r];
        edst[f] = ebase[srow * 7 + col];
    }
}

extern "C" void kernel_launch(void* const* d_in, const int* in_sizes, int n_in,
                              void* d_out, int out_size, void* d_ws, size_t ws_size,
                              hipStream_t stream) {
    const int*   paths      = (const int*)  d_in[0];
    const int*   edge_ids   = (const int*)  d_in[1];
    const int*   rand_lens  = (const int*)  d_in[2];
    const float* centrality = (const float*)d_in[3];
    // d_in[4] is k_path (scalar, known == 8)

    int* out_paths = (int*)d_out;
    int* out_edges = out_paths + (size_t)N_NODE * K_PATH * L_PATH;

    const int nodes_per_block = 8;   // 256 threads / 32 paths
    const int grid = N_NODE / nodes_per_block;  // 12500, exact

    path_sampling_kernel<<<grid, 256, 0, stream>>>(
        paths, edge_ids, rand_lens, centrality, out_paths, out_edges);
}